// Round 11
// baseline (379.642 us; speedup 1.0000x reference)
//
#include <hip/hip_runtime.h>

typedef _Float16 h8 __attribute__((ext_vector_type(8)));
typedef float    f4 __attribute__((ext_vector_type(4)));
typedef unsigned int u4 __attribute__((ext_vector_type(4)));

#define IMG_N 8
#define IMG_H 512
#define IMG_W 512
#define P_CNT 256
#define PSFN  64
#define SENS  1024

// fp16 tiles, parity-planar (halves):
// (0,0)@0 4096, (0,1)@4096 4096, (1,0)@8192 4032, (1,1)@12224 4032
#define TILE_HALVES 16256
#define TILES_BYTES ((size_t)IMG_N * P_CNT * TILE_HALVES * 2)   // 66,584,576

// Kfrag[p][cls][g][w]: h8 entry w = {K_cls[e = w+j-32][g]}_{j=0..7}, 16B-aligned
// by duplication.  w = t0 = 8q - m + (U0-16ut) + 32 in [0,89).
#define KW     90
#define KWB    (KW * 16)             // bytes per g-row
#define KFRAG_PER_P (4 * 33 * KW)    // 11880 entries

// BT[97 cols][40 r] fp16, col = c+32, zero-padded outside c in [0,32).
#define BT_COLS   97
#define BT_HALVES (BT_COLS * 40)

// ---------------- prep: build Kfrag fragment table (4 blocks per region) ---
__global__ __launch_bounds__(256) void svconv_prep(
    const float* __restrict__ psf, u4* __restrict__ kfrag)
{
    __shared__ float ps[PSFN * PSFN];
    __shared__ float Kc[4 * 33 * 33];      // Kc[cls][e][g], zero if invalid
    const int p = blockIdx.x >> 2, q4 = blockIdx.x & 3, tid = threadIdx.x;

    const float4* pp = (const float4*)(psf + (size_t)p * PSFN * PSFN);
    float4* pd = (float4*)ps;
    for (int i = tid; i < PSFN * PSFN / 4; i += 256) pd[i] = pp[i];
    __syncthreads();

    // K_cls[e][g] = Wp[a=2e-1+pi][b=2g-1+pj], Wp = 2x2-aggregated psf
    for (int idx = tid; idx < 4 * 33 * 33; idx += 256) {
        const int g = idx % 33, e = (idx / 33) % 33, cls = idx / 1089;
        const int pi = cls >> 1, pj = cls & 1;
        const int E = pi ? 32 : 33;
        float sv = 0.f;
        if (e < E) {
            const int a = 2 * e - 1 + pi, b = 2 * g - 1 + pj;
            #pragma unroll
            for (int du = 0; du < 2; ++du) {
                const int x = a + du;
                if ((unsigned)x < 64u) {
                    #pragma unroll
                    for (int dv = 0; dv < 2; ++dv) {
                        const int y = b + dv;
                        if ((unsigned)y < 64u) sv += ps[x * 64 + y];
                    }
                }
            }
        }
        Kc[idx] = sv;
    }
    __syncthreads();

    u4* kout = kfrag + (size_t)p * KFRAG_PER_P;
    for (int i2 = tid; i2 < KFRAG_PER_P / 4; i2 += 256) {
        const int idx = q4 * (KFRAG_PER_P / 4) + i2;
        const int w = idx % KW;
        const int g = (idx / KW) % 33;
        const int cls = idx / (KW * 33);
        h8 hv;
        #pragma unroll
        for (int j = 0; j < 8; ++j) {
            const int e = w + j - 32;
            const float v = ((unsigned)e < 33u) ? Kc[cls * 1089 + e * 33 + g] : 0.f;
            hv[j] = (_Float16)v;
        }
        kout[idx] = __builtin_bit_cast(u4, hv);
    }
}

// ---------------- main: MFMA, 2-deep pipelined global A, LDS B ------------
__global__ __launch_bounds__(256, 4) void svconv_main(
    const float* __restrict__ imgs, const u4* __restrict__ kfrag,
    _Float16* __restrict__ tiles)
{
    __shared__ __align__(16) _Float16 BT[BT_HALVES];

    const int bid = blockIdx.x;
    const int n = bid >> 8, p = bid & 255;
    const int bh = p & 15, bw = p >> 4;
    const int tid = threadIdx.x;
    const int wv = tid >> 6, lane = tid & 63;
    const int m = lane & 15, q = lane >> 4;

    for (int i = tid; i < BT_HALVES; i += 256) BT[i] = (_Float16)0.f;
    __syncthreads();
    {
        const int r0 = tid >> 5, c = tid & 31;
        const float* src = imgs + ((size_t)n * IMG_H + bh * 32) * IMG_W + bw * 32;
        for (int r = r0; r < 32; r += 8)
            BT[(c + 32) * 40 + r] = (_Float16)src[r * IMG_W + c];
    }
    __syncthreads();

    const int cls = wv, pi = cls >> 1, pj = cls & 1;
    const int U0 = pi ? 31 : 32;
    const char* btc = (const char*)BT + pj * 80;   // pj: c = v+g-32+pj

    int boff[4];
    #pragma unroll
    for (int vt = 0; vt < 4; ++vt) boff[vt] = (16 * vt + m) * 80 + q * 16;

    const char* ka[4];
    {
        const char* base = (const char*)(kfrag + (size_t)p * KFRAG_PER_P
                                         + cls * 33 * KW);
        #pragma unroll
        for (int ut = 0; ut < 4; ++ut) {
            const int t0 = 8 * q - m + (U0 - 16 * ut) + 32;   // in [0,88]
            ka[ut] = base + t0 * 16;
        }
    }

    f4 acc[4][4];
    #pragma unroll
    for (int ut = 0; ut < 4; ++ut)
        #pragma unroll
        for (int vt = 0; vt < 4; ++vt) acc[ut][vt] = (f4){0.f, 0.f, 0.f, 0.f};

    u4 A0[4], A1[4];
    #pragma unroll
    for (int ut = 0; ut < 4; ++ut) A0[ut] = *(const u4*)(ka[ut]);
    #pragma unroll
    for (int ut = 0; ut < 4; ++ut) A1[ut] = *(const u4*)(ka[ut] + KWB);

    #define DO_G(Abuf, G)                                                     \
        {                                                                     \
            h8 B[4];                                                          \
            _Pragma("unroll")                                                 \
            for (int vt = 0; vt < 4; ++vt)                                    \
                B[vt] = *(const h8*)(btc + boff[vt] + (G) * 80);              \
            _Pragma("unroll")                                                 \
            for (int ut = 0; ut < 4; ++ut)                                    \
                _Pragma("unroll")                                             \
                for (int vt = 0; vt < 4; ++vt)                                \
                    acc[ut][vt] = __builtin_amdgcn_mfma_f32_16x16x32_f16(     \
                        __builtin_bit_cast(h8, Abuf[ut]), B[vt],              \
                        acc[ut][vt], 0, 0, 0);                                \
        }

    #pragma unroll
    for (int gg = 0; gg < 16; ++gg) {
        DO_G(A0, 2 * gg);
        if (2 * gg + 2 < 33) {
            #pragma unroll
            for (int ut = 0; ut < 4; ++ut)
                A0[ut] = *(const u4*)(ka[ut] + (2 * gg + 2) * KWB);
        }
        DO_G(A1, 2 * gg + 1);
        if (2 * gg + 3 < 33) {
            #pragma unroll
            for (int ut = 0; ut < 4; ++ut)
                A1[ut] = *(const u4*)(ka[ut] + (2 * gg + 3) * KWB);
        }
    }
    DO_G(A0, 32);
    #undef DO_G

    // epilogue: C/D col=lane&15 (v), row=quad*4+reg (u); fp16 planar tile
    _Float16* tile = tiles + (size_t)(n * P_CNT + p) * TILE_HALVES;
    const int plane = pi ? (8192 + pj * 4032) : (pj * 4096);
    #pragma unroll
    for (int ut = 0; ut < 4; ++ut) {
        #pragma unroll
        for (int reg = 0; reg < 4; ++reg) {
            const int u = 16 * ut + 4 * q + reg;
            if (pi == 0 || u < 63) {                 // pi=1 u=63 -> i=127 discard
                _Float16* rp = tile + plane + u * 64 + m;
                #pragma unroll
                for (int vt = 0; vt < 4; ++vt)
                    rp[16 * vt] = (_Float16)acc[ut][vt][reg];
            }
        }
    }
}

// ---------------- gather: LDS-staged tile rows, branchless sum -------------
// Ls[k3][bww][pj][64] halves, k3 = bh - bhlo in [0,3); + 64-half zero slot.
#define LROWS 96
#define ZOFF  (LROWS * 64)   // 6144

__global__ __launch_bounds__(256) void svconv_gather(
    const _Float16* __restrict__ tiles, float* __restrict__ out)
{
    __shared__ __align__(16) _Float16 Ls[ZOFF + 64];

    const int b = blockIdx.x;
    const int n = b >> 10, x = b & 1023;
    const int tid = threadIdx.x;

    int bhlo = (x + 288) / 48 - 10; if (bhlo < 0) bhlo = 0;
    const int bhhi = (x < 113) ? -1 : (((x - 113) / 48) > 15 ? 15 : (x - 113) / 48);
    const _Float16* tn = tiles + (size_t)n * P_CNT * TILE_HALVES;

    // zero slot
    if (tid < 8) ((u4*)&Ls[ZOFF])[tid] = (u4){0u, 0u, 0u, 0u};
    // stage 96 rows x 8 u4 chunks = 768 chunks
    for (int c = tid; c < LROWS * 8; c += 256) {
        const int rid = c >> 3, w = c & 7;
        const int k3 = rid >> 5, rem = rid & 31, bww = rem >> 1, pjj = rem & 1;
        const int bhh = bhlo + k3;
        u4 val = (u4){0u, 0u, 0u, 0u};
        if (bhh <= bhhi) {
            const int ti = x - 113 - 48 * bhh;       // 0..126
            const int pii = ti & 1, uu = ti >> 1;
            const int base = (pii ? (8192 + pjj * 4032) : (pjj * 4096)) + uu * 64;
            val = *(const u4*)(tn + (size_t)(bww * 16 + bhh) * TILE_HALVES
                               + base + w * 8);
        }
        *(u4*)&Ls[rid * 64 + w * 8] = val;
    }
    __syncthreads();

    float* outrow = out + ((size_t)n << 20) + (size_t)x * SENS;
    #pragma unroll
    for (int yb = 0; yb < 4; ++yb) {
        const int y = yb * 256 + tid;
        int bwlo = (y + 288) / 48 - 10; if (bwlo < 0) bwlo = 0;
        const int bwhi = (y < 113) ? -1 : (((y - 113) / 48) > 15 ? 15 : (y - 113) / 48);
        const int t0 = y - 113 - 48 * bwlo;
        float s = 0.0f;
        #pragma unroll
        for (int k3 = 0; k3 < 3; ++k3) {
            #pragma unroll
            for (int kw = 0; kw < 3; ++kw) {
                const int bww = bwlo + kw;
                const int tj = t0 - 48 * kw;
                const int pjj = tj & 1, vv = tj >> 1;
                int idx = k3 * 2048 + (bww * 2 + pjj) * 64 + vv;
                idx = (bww <= bwhi) ? idx : ZOFF;    // invalid -> zero slot
                s += (float)Ls[idx];
            }
        }
        outrow[y] = s;   // every pixel written (uncovered rows get exact 0)
    }
}

extern "C" void kernel_launch(void* const* d_in, const int* in_sizes, int n_in,
                              void* d_out, int out_size, void* d_ws, size_t ws_size,
                              hipStream_t stream) {
    const float* imgs = (const float*)d_in[0];
    const float* psf  = (const float*)d_in[1];
    float* out = (float*)d_out;
    _Float16* tiles = (_Float16*)d_ws;                    // 66.6 MB
    u4* kfrag = (u4*)((char*)d_ws + TILES_BYTES);         // 48.7 MB (total 115 MB)

    svconv_prep<<<dim3(P_CNT * 4), dim3(256), 0, stream>>>(psf, kfrag);
    svconv_main<<<dim3(IMG_N * P_CNT), dim3(256), 0, stream>>>(imgs, kfrag, tiles);
    svconv_gather<<<dim3(IMG_N * SENS), dim3(256), 0, stream>>>(tiles, out);
}